// Round 9
// baseline (186.475 us; speedup 1.0000x reference)
//
#include <hip/hip_runtime.h>

// r23: INSTRUMENTATION ROUND. Kernels byte-identical to r8 (130.5us baseline).
// attn_kernel launched 4x (idempotent): attn_dur = (dur_us - 130.5)/3, and if
// attn >= ~44us its dispatches enter rocprof's top-5 with full counters.

#define T_SEQ 2048
#define DIM   768
#define NH    12
#define HD    64
#define KT    24     // k-tiles per fragment row (768/32)
#define TSZ   512    // elements per 16x32 fragment tile (64 lanes x 8)

typedef __attribute__((ext_vector_type(8))) short short8;
typedef __attribute__((ext_vector_type(4))) float floatx4;
typedef __attribute__((ext_vector_type(4))) unsigned short ushort4v;

#define MFMA16(a,b,c) __builtin_amdgcn_mfma_f32_16x16x32_bf16((a),(b),(c),0,0,0)

static __device__ __forceinline__ unsigned short f2bf(float f){
  union { float f; unsigned u; } v; v.f = f;
  unsigned r = v.u + 0x7fffu + ((v.u >> 16) & 1u);
  return (unsigned short)(r >> 16);
}
static __device__ __forceinline__ float bf2f(unsigned short u){
  union { unsigned u; float f; } v; v.u = ((unsigned)u) << 16;
  return v.f;
}
// pack two f32 -> bf16x2 (lo = first), exact RNE (same as f2bf)
static __device__ __forceinline__ unsigned pk2bf(float lo, float hi){
  return (unsigned)f2bf(lo) | ((unsigned)f2bf(hi) << 16);
}

// ---------------- fp32 -> bf16 convert + fragment-major swizzle -------------
__global__ void convert_kernel(const float* __restrict__ x,
                               const float* __restrict__ wq,
                               const float* __restrict__ wk,
                               const float* __restrict__ wv,
                               const float* __restrict__ wp,
                               unsigned short* __restrict__ xb,
                               unsigned short* __restrict__ wqkvb,
                               unsigned short* __restrict__ wpb){
  const int stride = gridDim.x * blockDim.x;
  const int i0 = blockIdx.x * blockDim.x + threadIdx.x;
  const int XC = T_SEQ * 96;
  const int WC = DIM * 96;

  for (int f = i0; f < XC; f += stride){
    const int r = f / 96, kc = f - r*96;
    const float* s = x + (size_t)r*DIM + kc*8;
    short8 o;
    #pragma unroll
    for (int e=0;e<8;e++) o[e] = (short)f2bf(s[e]);
    *(short8*)(xb + (size_t)(((r>>4)*KT + (kc>>2))*TSZ
                  + ((r&15) + 16*(kc&3))*8)) = o;
  }
  for (int f = i0; f < WC; f += stride){
    const int r = f / 96, kc = f - r*96;
    const size_t dst = (size_t)(((r>>4)*KT + (kc>>2))*TSZ
                     + ((r&15) + 16*(kc&3))*8);
    const size_t src = (size_t)r*DIM + kc*8;
    short8 oq, ok, ov, op;
    #pragma unroll
    for (int e=0;e<8;e++){
      oq[e] = (short)f2bf(wq[src+e]);
      ok[e] = (short)f2bf(wk[src+e]);
      ov[e] = (short)f2bf(wv[src+e]);
      op[e] = (short)f2bf(wp[src+e]);
    }
    *(short8*)(wqkvb + dst)              = oq;
    *(short8*)(wqkvb + (size_t)DIM*DIM   + dst) = ok;
    *(short8*)(wqkvb + (size_t)2*DIM*DIM + dst) = ov;
    *(short8*)(wpb   + dst)              = op;
  }
}

// ---------------- QKV projection + lerp + rmsnorm + rope (r1 exact) ---------
__global__ __launch_bounds__(64) void qkv_kernel(
    const unsigned short* __restrict__ xb,
    const unsigned short* __restrict__ wqkvb,
    const float* __restrict__ vi,
    const float* __restrict__ lambp,
    unsigned short* __restrict__ qb,
    unsigned short* __restrict__ kb,
    unsigned short* __restrict__ vb){
  const int l  = threadIdx.x;
  const int lr = l & 15, lq = l >> 4;
  const int rb = blockIdx.x, cb = blockIdx.y;
  const int mat = cb / NH, head = cb % NH;
  const int row0 = rb*32;

  floatx4 acc[2][4];
  #pragma unroll
  for (int i=0;i<2;i++)
    #pragma unroll
    for (int j=0;j<4;j++) acc[i][j] = (floatx4){0.f,0.f,0.f,0.f};

  const unsigned short* Ab = xb + (size_t)(rb*2)*KT*TSZ + l*8;
  const unsigned short* Bb = wqkvb + (size_t)mat*DIM*DIM
                           + (size_t)(head*4)*KT*TSZ + l*8;

  short8 a[2], b[4];
  #pragma unroll
  for (int rt=0;rt<2;rt++) a[rt] = *(const short8*)(Ab + (size_t)rt*KT*TSZ);
  #pragma unroll
  for (int ct=0;ct<4;ct++) b[ct] = *(const short8*)(Bb + (size_t)ct*KT*TSZ);

  for (int kt = 0; kt < KT; kt++){
    const int ktn = (kt + 1 < KT) ? kt + 1 : 0;
    short8 an[2], bn[4];
    #pragma unroll
    for (int rt=0;rt<2;rt++) an[rt] = *(const short8*)(Ab + (size_t)(rt*KT+ktn)*TSZ);
    #pragma unroll
    for (int ct=0;ct<4;ct++) bn[ct] = *(const short8*)(Bb + (size_t)(ct*KT+ktn)*TSZ);
    #pragma unroll
    for (int rt=0;rt<2;rt++)
      #pragma unroll
      for (int ct=0;ct<4;ct++)
        acc[rt][ct] = MFMA16(a[rt], b[ct], acc[rt][ct]);
    #pragma unroll
    for (int rt=0;rt<2;rt++) a[rt] = an[rt];
    #pragma unroll
    for (int ct=0;ct<4;ct++) b[ct] = bn[ct];
  }

  if (mat == 2){
    const float lamb = *lambp;
    unsigned short* Vh = vb + (size_t)head*T_SEQ*HD;
    #pragma unroll
    for (int rt=0;rt<2;rt++){
      const int tb = row0 + rt*16 + lq*4;
      #pragma unroll
      for (int ct=0;ct<4;ct++){
        const int d = ct*16 + lr;
        ushort4v pk;
        #pragma unroll
        for (int r=0;r<4;r++){
          float vv = (1.0f - lamb)*acc[rt][ct][r]
                   + lamb * vi[(size_t)(tb + r)*DIM + head*HD + d];
          pk[r] = f2bf(vv);
        }
        *(ushort4v*)(Vh + (size_t)((tb>>5)*4 + ct)*TSZ
                        + (lr + 16*((tb&31)>>3))*8 + (tb&7)) = pk;
      }
    }
  } else {
    unsigned short* dst = (mat==0 ? qb : kb) + (size_t)head*T_SEQ*HD;
    #pragma unroll
    for (int rt=0;rt<2;rt++){
      float ss[4];
      #pragma unroll
      for (int r=0;r<4;r++)
        ss[r] = acc[rt][0][r]*acc[rt][0][r] + acc[rt][1][r]*acc[rt][1][r]
              + acc[rt][2][r]*acc[rt][2][r] + acc[rt][3][r]*acc[rt][3][r];
      #pragma unroll
      for (int mm=1; mm<16; mm<<=1){
        #pragma unroll
        for (int r=0;r<4;r++) ss[r] += __shfl_xor(ss[r], mm);
      }
      float scl[4];
      #pragma unroll
      for (int r=0;r<4;r++)
        scl[r] = rsqrtf(ss[r]*(1.0f/64.0f) + 1.1920929e-7f);

      #pragma unroll
      for (int ct=0;ct<2;ct++){
        const int i = ct*16 + lr;
        const float inv = __expf(-(float)i * (9.210340371976184f/32.0f));
        const int lane8 = ((i>>3)&3)*16;
        #pragma unroll
        for (int r=0;r<4;r++){
          const int t = row0 + rt*16 + lq*4 + r;
          const float f = (float)t * inv;
          const float c = cosf(f), s = sinf(f);
          const float x1 = acc[rt][ct][r]*scl[r], x2 = acc[rt][ct+2][r]*scl[r];
          const size_t base = (size_t)((t>>4)*2)*TSZ
                            + ((t&15) + lane8)*8 + (i&7);
          dst[base]       = f2bf(x1*c + x2*s);
          dst[base + TSZ] = f2bf(x2*c - x1*s);
        }
      }
    }
  }
}

// ---------------- causal flash attention: swapped-QK^T (r8 exact) -----------
__global__ __launch_bounds__(512, 4) void attn_kernel(
    const unsigned short* __restrict__ qb,
    const unsigned short* __restrict__ kb,
    const unsigned short* __restrict__ vb,
    unsigned short* __restrict__ yb){   // swizzled fragment-major
  __shared__ __align__(16) char smem[8*64*40*2 + 8*32*4];  // Osh 40960 + lsh 1024
  unsigned short* Osh = (unsigned short*)smem;             // [8][64][40]
  float* lsh = (float*)(smem + 40960);                     // [8][32]

  const int w  = threadIdx.x >> 6;
  const int l  = threadIdx.x & 63;
  const int lr = l & 15, lq = l >> 4;
  const int head = blockIdx.y;

  const unsigned short* Q = qb + (size_t)head*T_SEQ*HD + l*8;
  const unsigned short* K = kb + (size_t)head*T_SEQ*HD + l*8;
  const unsigned short* V = vb + (size_t)head*T_SEQ*HD + l*8;

  const int sl0 = lr + ((lq & 1) << 5);   // src lane for frag dwords 0,1
  const int sl1 = sl0 + 16;               // src lane for frag dwords 2,3
  const bool hiK = (lq >= 2);             // this lane's frag keys are 16..31

  #pragma unroll
  for (int ph = 0; ph < 2; ph++){
    const int qs = ph ? (int)blockIdx.x : (63 - (int)blockIdx.x);  // heavy first
    const int q0 = qs*32;

    const short8 qf00 = *(const short8*)(Q + (size_t)(qs*2)*1024);
    const short8 qf01 = *(const short8*)(Q + (size_t)(qs*2)*1024 + TSZ);
    const short8 qf10 = *(const short8*)(Q + (size_t)(qs*2+1)*1024);
    const short8 qf11 = *(const short8*)(Q + (size_t)(qs*2+1)*1024 + TSZ);

    floatx4 OA[4], OB[4];   // O^T accumulators: (d = nt*16+lq*4+r, q = lr)
    #pragma unroll
    for (int nt=0; nt<4; nt++){
      OA[nt] = (floatx4){0.f,0.f,0.f,0.f};
      OB[nt] = (floatx4){0.f,0.f,0.f,0.f};
    }
    float lsA = 0.f, lsB = 0.f;   // denom partial for q = lr (tile A/B)

    const int ntile = qs + 1;
    for (int kt = w; kt < ntile; kt += 8){
      const int kbase = kt*32;
      const unsigned short* kp = K + (size_t)kt*2048;
      const unsigned short* vp = V + (size_t)kt*2048;
      short8 vf[4];
      #pragma unroll
      for (int nt=0; nt<4; nt++) vf[nt] = *(const short8*)(vp + (size_t)nt*TSZ);
      const short8 kf0 = *(const short8*)kp;
      const short8 kf1 = *(const short8*)(kp + TSZ);
      const short8 kf2 = *(const short8*)(kp + 2*TSZ);
      const short8 kf3 = *(const short8*)(kp + 3*TSZ);

      // S^T blocks: rows = keys (lq*4+r), cols = q (lr)
      floatx4 SA0 = (floatx4){0.f,0.f,0.f,0.f};
      floatx4 SA1 = (floatx4){0.f,0.f,0.f,0.f};
      floatx4 SB0 = (floatx4){0.f,0.f,0.f,0.f};
      floatx4 SB1 = (floatx4){0.f,0.f,0.f,0.f};
      SA0 = MFMA16(kf0, qf00, SA0);  SA0 = MFMA16(kf1, qf01, SA0);
      SA1 = MFMA16(kf2, qf00, SA1);  SA1 = MFMA16(kf3, qf01, SA1);
      SB0 = MFMA16(kf0, qf10, SB0);  SB0 = MFMA16(kf1, qf11, SB0);
      SB1 = MFMA16(kf2, qf10, SB1);  SB1 = MFMA16(kf3, qf11, SB1);

      // p = exp(s - 8), s = S*0.125  =>  exp2(S*0.125*log2e - 8*log2e)
      float pA0[4], pA1[4], pB0[4], pB1[4];
      const int keyr = kbase + lq*4;
      const int qA = q0 + lr;
      const int qB = qA + 16;
      #pragma unroll
      for (int r=0; r<4; r++){
        float eA0 = __builtin_amdgcn_exp2f(SA0[r]*0.18033688011112043f - 11.541560327111707f);
        float eA1 = __builtin_amdgcn_exp2f(SA1[r]*0.18033688011112043f - 11.541560327111707f);
        float eB0 = __builtin_amdgcn_exp2f(SB0[r]*0.18033688011112043f - 11.541560327111707f);
        float eB1 = __builtin_amdgcn_exp2f(SB1[r]*0.18033688011112043f - 11.541560327111707f);
        pA0[r] = (keyr + r      > qA) ? 0.f : eA0;
        pA1[r] = (keyr + 16 + r > qA) ? 0.f : eA1;
        pB0[r] = (keyr + r      > qB) ? 0.f : eB0;
        pB1[r] = (keyr + 16 + r > qB) ? 0.f : eB1;
        lsA += pA0[r] + pA1[r];
        lsB += pB0[r] + pB1[r];
      }

      // pack adjacent-key pairs (lane holds keys keyr..keyr+3 for q=lr)
      const unsigned uA0l = pk2bf(pA0[0], pA0[1]);
      const unsigned uA0h = pk2bf(pA0[2], pA0[3]);
      const unsigned uA1l = pk2bf(pA1[0], pA1[1]);
      const unsigned uA1h = pk2bf(pA1[2], pA1[3]);
      const unsigned uB0l = pk2bf(pB0[0], pB0[1]);
      const unsigned uB0h = pk2bf(pB0[2], pB0[3]);
      const unsigned uB1l = pk2bf(pB1[0], pB1[1]);
      const unsigned uB1h = pk2bf(pB1[2], pB1[3]);

      // redistribute to PV B-fragment: lane(lr=q,lq) dword j <- keys lq*8+2j,+1
      union { unsigned u[4]; short8 s; } fA, fB;
      {
        unsigned x0, x1;
        x0 = __shfl(uA0l, sl0); x1 = __shfl(uA1l, sl0); fA.u[0] = hiK ? x1 : x0;
        x0 = __shfl(uA0h, sl0); x1 = __shfl(uA1h, sl0); fA.u[1] = hiK ? x1 : x0;
        x0 = __shfl(uA0l, sl1); x1 = __shfl(uA1l, sl1); fA.u[2] = hiK ? x1 : x0;
        x0 = __shfl(uA0h, sl1); x1 = __shfl(uA1h, sl1); fA.u[3] = hiK ? x1 : x0;
        x0 = __shfl(uB0l, sl0); x1 = __shfl(uB1l, sl0); fB.u[0] = hiK ? x1 : x0;
        x0 = __shfl(uB0h, sl0); x1 = __shfl(uB1h, sl0); fB.u[1] = hiK ? x1 : x0;
        x0 = __shfl(uB0l, sl1); x1 = __shfl(uB1l, sl1); fB.u[2] = hiK ? x1 : x0;
        x0 = __shfl(uB0h, sl1); x1 = __shfl(uB1h, sl1); fB.u[3] = hiK ? x1 : x0;
      }

      // O^T += V^T . P : A = vf (lane=dim, regs=keys), B = redistributed P
      #pragma unroll
      for (int nt=0; nt<4; nt++) OA[nt] = MFMA16(vf[nt], fA.s, OA[nt]);
      #pragma unroll
      for (int nt=0; nt<4; nt++) OB[nt] = MFMA16(vf[nt], fB.s, OB[nt]);
    }

    // denominator: reduce across lq groups (q = lr is lane-local)
    lsA += __shfl_xor(lsA, 16);  lsA += __shfl_xor(lsA, 32);
    lsB += __shfl_xor(lsB, 16);  lsB += __shfl_xor(lsB, 32);

    if (lq == 0){
      lsh[w*32 + lr]      = lsA;
      lsh[w*32 + 16 + lr] = lsB;
    }
    #pragma unroll
    for (int nt=0; nt<4; nt++){
      ushort4v pk0, pk1;
      #pragma unroll
      for (int r=0; r<4; r++){ pk0[r] = f2bf(OA[nt][r]); pk1[r] = f2bf(OB[nt][r]); }
      *(ushort4v*)&Osh[((size_t)w*64 + l)*40 + nt*4]      = pk0;
      *(ushort4v*)&Osh[((size_t)w*64 + l)*40 + 16 + nt*4] = pk1;
    }
    __syncthreads();

    // merge: wave w handles (q-half = w>>2, dim-tile = w&3)
    {
      const int qh = w >> 2, nt = w & 3;
      float L = 0.f;
      float Of[4] = {0.f,0.f,0.f,0.f};
      #pragma unroll
      for (int ww=0; ww<8; ww++){
        L += lsh[ww*32 + qh*16 + lr];
        ushort4v pk = *(const ushort4v*)&Osh[((size_t)ww*64 + l)*40 + qh*16 + nt*4];
        #pragma unroll
        for (int r=0; r<4; r++) Of[r] += bf2f(pk[r]);
      }
      // lane holds O[q = q0+qh*16+lr][d = nt*16+lq*4+r]; write fragment-major
      const int qt = qs*2 + qh;
      const int colt = head*2 + (nt >> 1);
      const float invL = 1.0f / L;
      ushort4v pko;
      #pragma unroll
      for (int r=0; r<4; r++) pko[r] = f2bf(Of[r] * invL);
      *(ushort4v*)&yb[(size_t)(qt*KT + colt)*TSZ
                      + (size_t)(lr + 16*((nt&1)*2 + (lq>>1)))*8 + (lq&1)*4] = pko;
    }
    __syncthreads();   // all merges read Osh/lsh before next phase overwrites
  }
}

// ---------------- output projection (fp32 out, 16-row tile, r1 exact) -------
__global__ __launch_bounds__(64) void proj_kernel(
    const unsigned short* __restrict__ yb,
    const unsigned short* __restrict__ wpb,
    float* __restrict__ out){
  const int l  = threadIdx.x;
  const int lr = l & 15, lq = l >> 4;
  const int rb = blockIdx.x, cb = blockIdx.y;
  const int row0 = rb*16, col0 = cb*64;

  floatx4 acc[4];
  #pragma unroll
  for (int j=0;j<4;j++) acc[j] = (floatx4){0.f,0.f,0.f,0.f};

  const unsigned short* Ab = yb  + (size_t)rb*KT*TSZ + l*8;
  const unsigned short* Bb = wpb + (size_t)(cb*4)*KT*TSZ + l*8;

  short8 a, b[4];
  a = *(const short8*)Ab;
  #pragma unroll
  for (int ct=0;ct<4;ct++) b[ct] = *(const short8*)(Bb + (size_t)ct*KT*TSZ);

  for (int kt = 0; kt < KT; kt++){
    const int ktn = (kt + 1 < KT) ? kt + 1 : 0;
    short8 an, bn[4];
    an = *(const short8*)(Ab + (size_t)ktn*TSZ);
    #pragma unroll
    for (int ct=0;ct<4;ct++) bn[ct] = *(const short8*)(Bb + (size_t)(ct*KT+ktn)*TSZ);
    #pragma unroll
    for (int ct=0;ct<4;ct++)
      acc[ct] = MFMA16(a, b[ct], acc[ct]);
    a = an;
    #pragma unroll
    for (int ct=0;ct<4;ct++) b[ct] = bn[ct];
  }

  #pragma unroll
  for (int ct=0;ct<4;ct++){
    const int col = col0 + ct*16 + lr;
    #pragma unroll
    for (int r=0;r<4;r++){
      const int row = row0 + lq*4 + r;
      out[(size_t)row*DIM + col] = acc[ct][r];
    }
  }
}

extern "C" void kernel_launch(void* const* d_in, const int* in_sizes, int n_in,
                              void* d_out, int out_size, void* d_ws, size_t ws_size,
                              hipStream_t stream){
  const float* x   = (const float*)d_in[0];
  const float* vi  = (const float*)d_in[1];
  const float* Wq  = (const float*)d_in[2];
  const float* Wk  = (const float*)d_in[3];
  const float* Wv  = (const float*)d_in[4];
  const float* Wp  = (const float*)d_in[5];
  const float* lamb= (const float*)d_in[6];

  const size_t XN = (size_t)T_SEQ*DIM;   // 1572864
  const size_t WN = (size_t)DIM*DIM;     // 589824
  char* ws = (char*)d_ws;
  unsigned short* xb    = (unsigned short*)ws; ws += XN*2;
  unsigned short* wqkvb = (unsigned short*)ws; ws += 3*WN*2;
  unsigned short* wpb   = (unsigned short*)ws; ws += WN*2;
  unsigned short* qb    = (unsigned short*)ws; ws += XN*2;
  unsigned short* kb    = (unsigned short*)ws; ws += XN*2;
  unsigned short* vb    = (unsigned short*)ws; ws += XN*2;
  unsigned short* yb    = xb;  // alias: xb dead after qkv_kernel

  convert_kernel<<<1024, 256, 0, stream>>>(x, Wq, Wk, Wv, Wp, xb, wqkvb, wpb);
  qkv_kernel<<<dim3(64,36), 64, 0, stream>>>(xb, wqkvb, vi, lamb, qb, kb, vb);
  // attn x4 (idempotent): attn_dur = (dur_us - 130.5)/3; if >=44us it also
  // surfaces in the rocprof top-5 with VGPR/MfmaUtil/Occupancy.
  attn_kernel<<<dim3(32,12), 512, 0, stream>>>(qb, kb, vb, yb);
  attn_kernel<<<dim3(32,12), 512, 0, stream>>>(qb, kb, vb, yb);
  attn_kernel<<<dim3(32,12), 512, 0, stream>>>(qb, kb, vb, yb);
  attn_kernel<<<dim3(32,12), 512, 0, stream>>>(qb, kb, vb, yb);
  proj_kernel<<<dim3(128,12), 64, 0, stream>>>(yb, wpb, (float*)d_out);
}

// Round 10
// 130.282 us; speedup vs baseline: 1.4313x; 1.4313x over previous
//
#include <hip/hip_runtime.h>

#define T_SEQ 2048
#define DIM   768
#define NH    12
#define HD    64
#define KT    24     // k-tiles per fragment row (768/32)
#define TSZ   512    // elements per 16x32 fragment tile (64 lanes x 8)

typedef __attribute__((ext_vector_type(8))) short short8;
typedef __attribute__((ext_vector_type(4))) float floatx4;
typedef __attribute__((ext_vector_type(4))) unsigned short ushort4v;

#define MFMA16(a,b,c) __builtin_amdgcn_mfma_f32_16x16x32_bf16((a),(b),(c),0,0,0)

static __device__ __forceinline__ unsigned short f2bf(float f){
  union { float f; unsigned u; } v; v.f = f;
  unsigned r = v.u + 0x7fffu + ((v.u >> 16) & 1u);
  return (unsigned short)(r >> 16);
}
static __device__ __forceinline__ float bf2f(unsigned short u){
  union { unsigned u; float f; } v; v.u = ((unsigned)u) << 16;
  return v.f;
}
// pack two f32 -> bf16x2 (lo = first), exact RNE (same as f2bf)
static __device__ __forceinline__ unsigned pk2bf(float lo, float hi){
  return (unsigned)f2bf(lo) | ((unsigned)f2bf(hi) << 16);
}

// ---------------- fp32 -> bf16 convert + fragment-major swizzle -------------
__global__ void convert_kernel(const float* __restrict__ x,
                               const float* __restrict__ wq,
                               const float* __restrict__ wk,
                               const float* __restrict__ wv,
                               const float* __restrict__ wp,
                               unsigned short* __restrict__ xb,
                               unsigned short* __restrict__ wqkvb,
                               unsigned short* __restrict__ wpb){
  const int stride = gridDim.x * blockDim.x;
  const int i0 = blockIdx.x * blockDim.x + threadIdx.x;
  const int XC = T_SEQ * 96;
  const int WC = DIM * 96;

  for (int f = i0; f < XC; f += stride){
    const int r = f / 96, kc = f - r*96;
    const float* s = x + (size_t)r*DIM + kc*8;
    short8 o;
    #pragma unroll
    for (int e=0;e<8;e++) o[e] = (short)f2bf(s[e]);
    *(short8*)(xb + (size_t)(((r>>4)*KT + (kc>>2))*TSZ
                  + ((r&15) + 16*(kc&3))*8)) = o;
  }
  for (int f = i0; f < WC; f += stride){
    const int r = f / 96, kc = f - r*96;
    const size_t dst = (size_t)(((r>>4)*KT + (kc>>2))*TSZ
                     + ((r&15) + 16*(kc&3))*8);
    const size_t src = (size_t)r*DIM + kc*8;
    short8 oq, ok, ov, op;
    #pragma unroll
    for (int e=0;e<8;e++){
      oq[e] = (short)f2bf(wq[src+e]);
      ok[e] = (short)f2bf(wk[src+e]);
      ov[e] = (short)f2bf(wv[src+e]);
      op[e] = (short)f2bf(wp[src+e]);
    }
    *(short8*)(wqkvb + dst)              = oq;
    *(short8*)(wqkvb + (size_t)DIM*DIM   + dst) = ok;
    *(short8*)(wqkvb + (size_t)2*DIM*DIM + dst) = ov;
    *(short8*)(wpb   + dst)              = op;
  }
}

// ---------------- QKV projection + lerp + rmsnorm + rope --------------------
// r24: XCD-aware chunked swizzle (T1). qkv's hot set (xb 3MB + wqkvb 3.4MB =
// 6.4MB) exceeds the 4MB per-XCD L2; default round-robin dispatch makes every
// XCD demand BOTH matrices -> all 8 L2s thrash (r0: FETCH 24.7MB vs 12.4MB
// ideal, 2x HBM over-fetch at ~900cy misses on the dependent chain — explains
// why occupancy/pipelining/LDS-staging probes were all null). Remap so each
// XCD owns a CONTIGUOUS cb range: per-XCD set = A 3MB + 4.5 B-panels (432KB)
// = 3.4MB < 4MB. wrk = (bid%8)*288 + bid/8 (bijective, 2304 % 8 == 0).
__global__ __launch_bounds__(64) void qkv_kernel(
    const unsigned short* __restrict__ xb,
    const unsigned short* __restrict__ wqkvb,
    const float* __restrict__ vi,
    const float* __restrict__ lambp,
    unsigned short* __restrict__ qb,
    unsigned short* __restrict__ kb,
    unsigned short* __restrict__ vb){
  const int l  = threadIdx.x;
  const int lr = l & 15, lq = l >> 4;
  const int bid = blockIdx.x;
  const int wrk = (bid & 7) * 288 + (bid >> 3);
  const int cb = wrk / 64;          // contiguous per XCD (B-panel locality)
  const int rb = wrk - cb * 64;
  const int mat = cb / NH, head = cb % NH;
  const int row0 = rb*32;

  floatx4 acc[2][4];
  #pragma unroll
  for (int i=0;i<2;i++)
    #pragma unroll
    for (int j=0;j<4;j++) acc[i][j] = (floatx4){0.f,0.f,0.f,0.f};

  const unsigned short* Ab = xb + (size_t)(rb*2)*KT*TSZ + l*8;
  const unsigned short* Bb = wqkvb + (size_t)mat*DIM*DIM
                           + (size_t)(head*4)*KT*TSZ + l*8;

  short8 a[2], b[4];
  #pragma unroll
  for (int rt=0;rt<2;rt++) a[rt] = *(const short8*)(Ab + (size_t)rt*KT*TSZ);
  #pragma unroll
  for (int ct=0;ct<4;ct++) b[ct] = *(const short8*)(Bb + (size_t)ct*KT*TSZ);

  for (int kt = 0; kt < KT; kt++){
    const int ktn = (kt + 1 < KT) ? kt + 1 : 0;
    short8 an[2], bn[4];
    #pragma unroll
    for (int rt=0;rt<2;rt++) an[rt] = *(const short8*)(Ab + (size_t)(rt*KT+ktn)*TSZ);
    #pragma unroll
    for (int ct=0;ct<4;ct++) bn[ct] = *(const short8*)(Bb + (size_t)(ct*KT+ktn)*TSZ);
    #pragma unroll
    for (int rt=0;rt<2;rt++)
      #pragma unroll
      for (int ct=0;ct<4;ct++)
        acc[rt][ct] = MFMA16(a[rt], b[ct], acc[rt][ct]);
    #pragma unroll
    for (int rt=0;rt<2;rt++) a[rt] = an[rt];
    #pragma unroll
    for (int ct=0;ct<4;ct++) b[ct] = bn[ct];
  }

  if (mat == 2){
    const float lamb = *lambp;
    unsigned short* Vh = vb + (size_t)head*T_SEQ*HD;
    #pragma unroll
    for (int rt=0;rt<2;rt++){
      const int tb = row0 + rt*16 + lq*4;
      #pragma unroll
      for (int ct=0;ct<4;ct++){
        const int d = ct*16 + lr;
        ushort4v pk;
        #pragma unroll
        for (int r=0;r<4;r++){
          float vv = (1.0f - lamb)*acc[rt][ct][r]
                   + lamb * vi[(size_t)(tb + r)*DIM + head*HD + d];
          pk[r] = f2bf(vv);
        }
        *(ushort4v*)(Vh + (size_t)((tb>>5)*4 + ct)*TSZ
                        + (lr + 16*((tb&31)>>3))*8 + (tb&7)) = pk;
      }
    }
  } else {
    unsigned short* dst = (mat==0 ? qb : kb) + (size_t)head*T_SEQ*HD;
    #pragma unroll
    for (int rt=0;rt<2;rt++){
      float ss[4];
      #pragma unroll
      for (int r=0;r<4;r++)
        ss[r] = acc[rt][0][r]*acc[rt][0][r] + acc[rt][1][r]*acc[rt][1][r]
              + acc[rt][2][r]*acc[rt][2][r] + acc[rt][3][r]*acc[rt][3][r];
      #pragma unroll
      for (int mm=1; mm<16; mm<<=1){
        #pragma unroll
        for (int r=0;r<4;r++) ss[r] += __shfl_xor(ss[r], mm);
      }
      float scl[4];
      #pragma unroll
      for (int r=0;r<4;r++)
        scl[r] = rsqrtf(ss[r]*(1.0f/64.0f) + 1.1920929e-7f);

      #pragma unroll
      for (int ct=0;ct<2;ct++){
        const int i = ct*16 + lr;
        const float inv = __expf(-(float)i * (9.210340371976184f/32.0f));
        const int lane8 = ((i>>3)&3)*16;
        #pragma unroll
        for (int r=0;r<4;r++){
          const int t = row0 + rt*16 + lq*4 + r;
          const float f = (float)t * inv;
          const float c = cosf(f), s = sinf(f);
          const float x1 = acc[rt][ct][r]*scl[r], x2 = acc[rt][ct+2][r]*scl[r];
          const size_t base = (size_t)((t>>4)*2)*TSZ
                            + ((t&15) + lane8)*8 + (i&7);
          dst[base]       = f2bf(x1*c + x2*s);
          dst[base + TSZ] = f2bf(x2*c - x1*s);
        }
      }
    }
  }
}

// ---------------- causal flash attention: swapped-QK^T (r8 exact) -----------
__global__ __launch_bounds__(512, 4) void attn_kernel(
    const unsigned short* __restrict__ qb,
    const unsigned short* __restrict__ kb,
    const unsigned short* __restrict__ vb,
    unsigned short* __restrict__ yb){   // swizzled fragment-major
  __shared__ __align__(16) char smem[8*64*40*2 + 8*32*4];  // Osh 40960 + lsh 1024
  unsigned short* Osh = (unsigned short*)smem;             // [8][64][40]
  float* lsh = (float*)(smem + 40960);                     // [8][32]

  const int w  = threadIdx.x >> 6;
  const int l  = threadIdx.x & 63;
  const int lr = l & 15, lq = l >> 4;
  const int head = blockIdx.y;

  const unsigned short* Q = qb + (size_t)head*T_SEQ*HD + l*8;
  const unsigned short* K = kb + (size_t)head*T_SEQ*HD + l*8;
  const unsigned short* V = vb + (size_t)head*T_SEQ*HD + l*8;

  const int sl0 = lr + ((lq & 1) << 5);   // src lane for frag dwords 0,1
  const int sl1 = sl0 + 16;               // src lane for frag dwords 2,3
  const bool hiK = (lq >= 2);             // this lane's frag keys are 16..31

  #pragma unroll
  for (int ph = 0; ph < 2; ph++){
    const int qs = ph ? (int)blockIdx.x : (63 - (int)blockIdx.x);  // heavy first
    const int q0 = qs*32;

    const short8 qf00 = *(const short8*)(Q + (size_t)(qs*2)*1024);
    const short8 qf01 = *(const short8*)(Q + (size_t)(qs*2)*1024 + TSZ);
    const short8 qf10 = *(const short8*)(Q + (size_t)(qs*2+1)*1024);
    const short8 qf11 = *(const short8*)(Q + (size_t)(qs*2+1)*1024 + TSZ);

    floatx4 OA[4], OB[4];   // O^T accumulators: (d = nt*16+lq*4+r, q = lr)
    #pragma unroll
    for (int nt=0; nt<4; nt++){
      OA[nt] = (floatx4){0.f,0.f,0.f,0.f};
      OB[nt] = (floatx4){0.f,0.f,0.f,0.f};
    }
    float lsA = 0.f, lsB = 0.f;   // denom partial for q = lr (tile A/B)

    const int ntile = qs + 1;
    for (int kt = w; kt < ntile; kt += 8){
      const int kbase = kt*32;
      const unsigned short* kp = K + (size_t)kt*2048;
      const unsigned short* vp = V + (size_t)kt*2048;
      short8 vf[4];
      #pragma unroll
      for (int nt=0; nt<4; nt++) vf[nt] = *(const short8*)(vp + (size_t)nt*TSZ);
      const short8 kf0 = *(const short8*)kp;
      const short8 kf1 = *(const short8*)(kp + TSZ);
      const short8 kf2 = *(const short8*)(kp + 2*TSZ);
      const short8 kf3 = *(const short8*)(kp + 3*TSZ);

      // S^T blocks: rows = keys (lq*4+r), cols = q (lr)
      floatx4 SA0 = (floatx4){0.f,0.f,0.f,0.f};
      floatx4 SA1 = (floatx4){0.f,0.f,0.f,0.f};
      floatx4 SB0 = (floatx4){0.f,0.f,0.f,0.f};
      floatx4 SB1 = (floatx4){0.f,0.f,0.f,0.f};
      SA0 = MFMA16(kf0, qf00, SA0);  SA0 = MFMA16(kf1, qf01, SA0);
      SA1 = MFMA16(kf2, qf00, SA1);  SA1 = MFMA16(kf3, qf01, SA1);
      SB0 = MFMA16(kf0, qf10, SB0);  SB0 = MFMA16(kf1, qf11, SB0);
      SB1 = MFMA16(kf2, qf10, SB1);  SB1 = MFMA16(kf3, qf11, SB1);

      // p = exp(s - 8), s = S*0.125  =>  exp2(S*0.125*log2e - 8*log2e)
      float pA0[4], pA1[4], pB0[4], pB1[4];
      const int keyr = kbase + lq*4;
      const int qA = q0 + lr;
      const int qB = qA + 16;
      #pragma unroll
      for (int r=0; r<4; r++){
        float eA0 = __builtin_amdgcn_exp2f(SA0[r]*0.18033688011112043f - 11.541560327111707f);
        float eA1 = __builtin_amdgcn_exp2f(SA1[r]*0.18033688011112043f - 11.541560327111707f);
        float eB0 = __builtin_amdgcn_exp2f(SB0[r]*0.18033688011112043f - 11.541560327111707f);
        float eB1 = __builtin_amdgcn_exp2f(SB1[r]*0.18033688011112043f - 11.541560327111707f);
        pA0[r] = (keyr + r      > qA) ? 0.f : eA0;
        pA1[r] = (keyr + 16 + r > qA) ? 0.f : eA1;
        pB0[r] = (keyr + r      > qB) ? 0.f : eB0;
        pB1[r] = (keyr + 16 + r > qB) ? 0.f : eB1;
        lsA += pA0[r] + pA1[r];
        lsB += pB0[r] + pB1[r];
      }

      // pack adjacent-key pairs (lane holds keys keyr..keyr+3 for q=lr)
      const unsigned uA0l = pk2bf(pA0[0], pA0[1]);
      const unsigned uA0h = pk2bf(pA0[2], pA0[3]);
      const unsigned uA1l = pk2bf(pA1[0], pA1[1]);
      const unsigned uA1h = pk2bf(pA1[2], pA1[3]);
      const unsigned uB0l = pk2bf(pB0[0], pB0[1]);
      const unsigned uB0h = pk2bf(pB0[2], pB0[3]);
      const unsigned uB1l = pk2bf(pB1[0], pB1[1]);
      const unsigned uB1h = pk2bf(pB1[2], pB1[3]);

      // redistribute to PV B-fragment: lane(lr=q,lq) dword j <- keys lq*8+2j,+1
      union { unsigned u[4]; short8 s; } fA, fB;
      {
        unsigned x0, x1;
        x0 = __shfl(uA0l, sl0); x1 = __shfl(uA1l, sl0); fA.u[0] = hiK ? x1 : x0;
        x0 = __shfl(uA0h, sl0); x1 = __shfl(uA1h, sl0); fA.u[1] = hiK ? x1 : x0;
        x0 = __shfl(uA0l, sl1); x1 = __shfl(uA1l, sl1); fA.u[2] = hiK ? x1 : x0;
        x0 = __shfl(uA0h, sl1); x1 = __shfl(uA1h, sl1); fA.u[3] = hiK ? x1 : x0;
        x0 = __shfl(uB0l, sl0); x1 = __shfl(uB1l, sl0); fB.u[0] = hiK ? x1 : x0;
        x0 = __shfl(uB0h, sl0); x1 = __shfl(uB1h, sl0); fB.u[1] = hiK ? x1 : x0;
        x0 = __shfl(uB0l, sl1); x1 = __shfl(uB1l, sl1); fB.u[2] = hiK ? x1 : x0;
        x0 = __shfl(uB0h, sl1); x1 = __shfl(uB1h, sl1); fB.u[3] = hiK ? x1 : x0;
      }

      // O^T += V^T . P : A = vf (lane=dim, regs=keys), B = redistributed P
      #pragma unroll
      for (int nt=0; nt<4; nt++) OA[nt] = MFMA16(vf[nt], fA.s, OA[nt]);
      #pragma unroll
      for (int nt=0; nt<4; nt++) OB[nt] = MFMA16(vf[nt], fB.s, OB[nt]);
    }

    // denominator: reduce across lq groups (q = lr is lane-local)
    lsA += __shfl_xor(lsA, 16);  lsA += __shfl_xor(lsA, 32);
    lsB += __shfl_xor(lsB, 16);  lsB += __shfl_xor(lsB, 32);

    if (lq == 0){
      lsh[w*32 + lr]      = lsA;
      lsh[w*32 + 16 + lr] = lsB;
    }
    #pragma unroll
    for (int nt=0; nt<4; nt++){
      ushort4v pk0, pk1;
      #pragma unroll
      for (int r=0; r<4; r++){ pk0[r] = f2bf(OA[nt][r]); pk1[r] = f2bf(OB[nt][r]); }
      *(ushort4v*)&Osh[((size_t)w*64 + l)*40 + nt*4]      = pk0;
      *(ushort4v*)&Osh[((size_t)w*64 + l)*40 + 16 + nt*4] = pk1;
    }
    __syncthreads();

    // merge: wave w handles (q-half = w>>2, dim-tile = w&3)
    {
      const int qh = w >> 2, nt = w & 3;
      float L = 0.f;
      float Of[4] = {0.f,0.f,0.f,0.f};
      #pragma unroll
      for (int ww=0; ww<8; ww++){
        L += lsh[ww*32 + qh*16 + lr];
        ushort4v pk = *(const ushort4v*)&Osh[((size_t)ww*64 + l)*40 + qh*16 + nt*4];
        #pragma unroll
        for (int r=0; r<4; r++) Of[r] += bf2f(pk[r]);
      }
      // lane holds O[q = q0+qh*16+lr][d = nt*16+lq*4+r]; write fragment-major
      const int qt = qs*2 + qh;
      const int colt = head*2 + (nt >> 1);
      const float invL = 1.0f / L;
      ushort4v pko;
      #pragma unroll
      for (int r=0; r<4; r++) pko[r] = f2bf(Of[r] * invL);
      *(ushort4v*)&yb[(size_t)(qt*KT + colt)*TSZ
                      + (size_t)(lr + 16*((nt&1)*2 + (lq>>1)))*8 + (lq&1)*4] = pko;
    }
    __syncthreads();   // all merges read Osh/lsh before next phase overwrites
  }
}

// ---------------- output projection (fp32 out, 16-row tile) -----------------
// r24: XCD-aware chunked swizzle (yb 3MB + wpb 1.1MB = 4.1MB > 4MB L2 per
// XCD under round-robin; per-XCD after swizzle = yb 3MB + 1.5 panels 144KB).
// wrk = (bid%8)*192 + bid/8 (bijective, 1536 % 8 == 0).
__global__ __launch_bounds__(64) void proj_kernel(
    const unsigned short* __restrict__ yb,
    const unsigned short* __restrict__ wpb,
    float* __restrict__ out){
  const int l  = threadIdx.x;
  const int lr = l & 15, lq = l >> 4;
  const int bid = blockIdx.x;
  const int wrk = (bid & 7) * 192 + (bid >> 3);
  const int cb = wrk / 128;         // contiguous per XCD
  const int rb = wrk - cb * 128;
  const int row0 = rb*16, col0 = cb*64;

  floatx4 acc[4];
  #pragma unroll
  for (int j=0;j<4;j++) acc[j] = (floatx4){0.f,0.f,0.f,0.f};

  const unsigned short* Ab = yb  + (size_t)rb*KT*TSZ + l*8;
  const unsigned short* Bb = wpb + (size_t)(cb*4)*KT*TSZ + l*8;

  short8 a, b[4];
  a = *(const short8*)Ab;
  #pragma unroll
  for (int ct=0;ct<4;ct++) b[ct] = *(const short8*)(Bb + (size_t)ct*KT*TSZ);

  for (int kt = 0; kt < KT; kt++){
    const int ktn = (kt + 1 < KT) ? kt + 1 : 0;
    short8 an, bn[4];
    an = *(const short8*)(Ab + (size_t)ktn*TSZ);
    #pragma unroll
    for (int ct=0;ct<4;ct++) bn[ct] = *(const short8*)(Bb + (size_t)(ct*KT+ktn)*TSZ);
    #pragma unroll
    for (int ct=0;ct<4;ct++)
      acc[ct] = MFMA16(a, b[ct], acc[ct]);
    a = an;
    #pragma unroll
    for (int ct=0;ct<4;ct++) b[ct] = bn[ct];
  }

  #pragma unroll
  for (int ct=0;ct<4;ct++){
    const int col = col0 + ct*16 + lr;
    #pragma unroll
    for (int r=0;r<4;r++){
      const int row = row0 + lq*4 + r;
      out[(size_t)row*DIM + col] = acc[ct][r];
    }
  }
}

extern "C" void kernel_launch(void* const* d_in, const int* in_sizes, int n_in,
                              void* d_out, int out_size, void* d_ws, size_t ws_size,
                              hipStream_t stream){
  const float* x   = (const float*)d_in[0];
  const float* vi  = (const float*)d_in[1];
  const float* Wq  = (const float*)d_in[2];
  const float* Wk  = (const float*)d_in[3];
  const float* Wv  = (const float*)d_in[4];
  const float* Wp  = (const float*)d_in[5];
  const float* lamb= (const float*)d_in[6];

  const size_t XN = (size_t)T_SEQ*DIM;   // 1572864
  const size_t WN = (size_t)DIM*DIM;     // 589824
  char* ws = (char*)d_ws;
  unsigned short* xb    = (unsigned short*)ws; ws += XN*2;
  unsigned short* wqkvb = (unsigned short*)ws; ws += 3*WN*2;
  unsigned short* wpb   = (unsigned short*)ws; ws += WN*2;
  unsigned short* qb    = (unsigned short*)ws; ws += XN*2;
  unsigned short* kb    = (unsigned short*)ws; ws += XN*2;
  unsigned short* vb    = (unsigned short*)ws; ws += XN*2;
  unsigned short* yb    = xb;  // alias: xb dead after qkv_kernel

  convert_kernel<<<1024, 256, 0, stream>>>(x, Wq, Wk, Wv, Wp, xb, wqkvb, wpb);
  qkv_kernel<<<2304, 64, 0, stream>>>(xb, wqkvb, vi, lamb, qb, kb, vb);
  attn_kernel<<<dim3(32,12), 512, 0, stream>>>(qb, kb, vb, yb);
  proj_kernel<<<1536, 64, 0, stream>>>(yb, wpb, (float*)d_out);
}